// Round 2
// baseline (415.847 us; speedup 1.0000x reference)
//
#include <hip/hip_runtime.h>
#include <math.h>

#define HH 96
#define WW 96
#define NPIX (HH*WW)          // 9216
#define CC 320
#define GG 32
#define CPG 10                // channels per group
#define YT 6                  // y-tiles per image
#define TR 16                 // rows per tile
#define THREADS1 384          // 24 chunks/row * 16 rows

// ---------------------------------------------------------------------------
// Kernel 1 (single pass over x): per (b, group, ytile) block.
// Each thread owns one 4-pixel chunk; loops over the group's 10 channels,
// computing conv u once, accumulating:
//   P[b,g,p]   += (proj_w*gn_w)[c] * u        (stats-independent plane)
//   s1,s2      += h, h^2  with h = u + dw_b   (GN statistics)
// ---------------------------------------------------------------------------
__global__ __launch_bounds__(THREADS1)
void k_main(const float* __restrict__ x, const float* __restrict__ dw_w,
            const float* __restrict__ dw_b, const float* __restrict__ gn_w,
            const float* __restrict__ proj_w,
            float* __restrict__ P, float* __restrict__ partials) {
  const int bid = blockIdx.x;
  const int yt = bid % YT;
  const int t  = bid / YT;
  const int gr = t & 31;
  const int b  = t >> 5;

  __shared__ float wsm[CPG * 9], ssm[CPG], bsm[CPG];
  const int tid = threadIdx.x;
  if (tid < CPG * 9) wsm[tid] = dw_w[gr * CPG * 9 + tid];
  if (tid < CPG) {
    int c = gr * CPG + tid;
    ssm[tid] = proj_w[c] * gn_w[c];
    bsm[tid] = dw_b[c];
  }
  __syncthreads();

  const int xc = tid % 24;            // chunk column (4 px each)
  const int y  = tid / 24;            // 0..15
  const int Y  = yt * TR + y;
  const float* xg = x + ((size_t)(b * CC + gr * CPG)) * NPIX;

  float p0 = 0.f, p1 = 0.f, p2 = 0.f, p3 = 0.f, s1 = 0.f, s2 = 0.f;

  for (int cl = 0; cl < CPG; ++cl) {
    const float* img = xg + cl * NPIX;
    float v[3][6];
    #pragma unroll
    for (int ky = 0; ky < 3; ++ky) {
      int yy = Y + ky - 1;
      if (yy >= 0 && yy < HH) {
        const float* row = img + yy * WW + xc * 4;
        float4 m = *(const float4*)row;
        v[ky][1] = m.x; v[ky][2] = m.y; v[ky][3] = m.z; v[ky][4] = m.w;
        v[ky][0] = (xc > 0)  ? row[-1] : 0.f;
        v[ky][5] = (xc < 23) ? row[4]  : 0.f;
      } else {
        v[ky][0] = v[ky][1] = v[ky][2] = v[ky][3] = v[ky][4] = v[ky][5] = 0.f;
      }
    }
    const float* wp = &wsm[cl * 9];
    float u[4];
    #pragma unroll
    for (int j = 0; j < 4; ++j) {
      float uu = 0.f;
      #pragma unroll
      for (int ky = 0; ky < 3; ++ky)
        #pragma unroll
        for (int kx = 0; kx < 3; ++kx)
          uu = fmaf(wp[ky * 3 + kx], v[ky][j + kx], uu);
      u[j] = uu;
    }
    const float sc = ssm[cl], bias = bsm[cl];
    p0 = fmaf(sc, u[0], p0);
    p1 = fmaf(sc, u[1], p1);
    p2 = fmaf(sc, u[2], p2);
    p3 = fmaf(sc, u[3], p3);
    float h0 = u[0] + bias, h1 = u[1] + bias, h2 = u[2] + bias, h3 = u[3] + bias;
    s1 += (h0 + h1) + (h2 + h3);
    s2 += fmaf(h0, h0, h1 * h1) + fmaf(h2, h2, h3 * h3);
  }

  // store the group plane (coalesced float4)
  size_t pidx = ((size_t)(b * GG + gr)) * NPIX + (size_t)Y * WW + xc * 4;
  *(float4*)&P[pidx] = make_float4(p0, p1, p2, p3);

  // block-reduce s1,s2 (6 waves)
  #pragma unroll
  for (int off = 32; off; off >>= 1) {
    s1 += __shfl_down(s1, off);
    s2 += __shfl_down(s2, off);
  }
  __shared__ float r1[6], r2[6];
  if ((tid & 63) == 0) { r1[tid >> 6] = s1; r2[tid >> 6] = s2; }
  __syncthreads();
  if (tid == 0) {
    float a = 0.f, q = 0.f;
    #pragma unroll
    for (int i = 0; i < 6; ++i) { a += r1[i]; q += r2[i]; }
    size_t o = (((size_t)(b * GG + gr)) * YT + yt) * 2;
    partials[o]     = a;
    partials[o + 1] = q;
  }
}

// ---------------------------------------------------------------------------
// Kernel 2: combine partial stats -> rinv per (b,group); per-batch scalar D.
// One block, 512 threads = (b,group).
// ---------------------------------------------------------------------------
__global__ __launch_bounds__(512)
void k_coef(const float* __restrict__ partials, const float* __restrict__ dw_b,
            const float* __restrict__ gn_w, const float* __restrict__ gn_b,
            const float* __restrict__ proj_w, const float* __restrict__ proj_b,
            float* __restrict__ rv, float* __restrict__ D) {
  const int tid = threadIdx.x;        // 0..511
  const int b = tid >> 5, gr = tid & 31;
  float s1 = 0.f, s2 = 0.f;
  #pragma unroll
  for (int t = 0; t < YT; ++t) {
    size_t o = (((size_t)(b * GG + gr)) * YT + t) * 2;
    s1 += partials[o];
    s2 += partials[o + 1];
  }
  const float invN = 1.f / (float)(CPG * NPIX);
  float mean = s1 * invN;
  float var  = s2 * invN - mean * mean;
  float rinv = rsqrtf(var + 1e-5f);
  float K = 0.f, E = 0.f;
  #pragma unroll
  for (int i = 0; i < CPG; ++i) {
    int c = gr * CPG + i;
    float pg = proj_w[c] * gn_w[c];
    K = fmaf(pg, dw_b[c] - mean, K);
    E = fmaf(proj_w[c], gn_b[c], E);
  }
  rv[tid] = rinv;
  float contrib = fmaf(rinv, K, E);
  #pragma unroll
  for (int m = 16; m; m >>= 1) contrib += __shfl_xor(contrib, m, 32);
  if (gr == 0) D[b] = contrib + proj_b[0];
}

// ---------------------------------------------------------------------------
// Kernel 3: out[b,p] = sigmoid( sum_g rv[b,g]*P[b,g,p] + D[b] )
// 144 blocks x 256 threads, float4 per thread.
// ---------------------------------------------------------------------------
__global__ __launch_bounds__(256)
void k_out(const float* __restrict__ P, const float* __restrict__ rv,
           const float* __restrict__ D, float* __restrict__ out) {
  const int b   = blockIdx.x / 9;
  const int blk = blockIdx.x % 9;
  __shared__ float rs[GG];
  __shared__ float Ds;
  if (threadIdx.x < GG) rs[threadIdx.x] = rv[b * GG + threadIdx.x];
  if (threadIdx.x == 0) Ds = D[b];
  __syncthreads();

  const int p = (blk * 256 + threadIdx.x) * 4;    // 9*256*4 = 9216
  const float* Pb = P + (size_t)b * GG * NPIX + p;
  float g0 = 0.f, g1 = 0.f, g2 = 0.f, g3 = 0.f;
  #pragma unroll 8
  for (int gr = 0; gr < GG; ++gr) {
    float4 v = *(const float4*)(Pb + (size_t)gr * NPIX);
    float r = rs[gr];
    g0 = fmaf(r, v.x, g0);
    g1 = fmaf(r, v.y, g1);
    g2 = fmaf(r, v.z, g2);
    g3 = fmaf(r, v.w, g3);
  }
  const float d = Ds;
  float4 o;
  o.x = 1.f / (1.f + expf(-(g0 + d)));
  o.y = 1.f / (1.f + expf(-(g1 + d)));
  o.z = 1.f / (1.f + expf(-(g2 + d)));
  o.w = 1.f / (1.f + expf(-(g3 + d)));
  *(float4*)&out[(size_t)b * NPIX + p] = o;
}

// ---------------------------------------------------------------------------
extern "C" void kernel_launch(void* const* d_in, const int* in_sizes, int n_in,
                              void* d_out, int out_size, void* d_ws, size_t ws_size,
                              hipStream_t stream) {
  const float* x      = (const float*)d_in[0];
  const float* dw_w   = (const float*)d_in[1];
  const float* dw_b   = (const float*)d_in[2];
  const float* gn_w   = (const float*)d_in[3];
  const float* gn_b   = (const float*)d_in[4];
  const float* proj_w = (const float*)d_in[5];
  const float* proj_b = (const float*)d_in[6];
  float* out = (float*)d_out;

  // workspace layout
  const size_t P_BYTES = (size_t)16 * GG * NPIX * 4;     // 18,874,368
  float* P        = (float*)d_ws;
  float* partials = (float*)((char*)d_ws + P_BYTES);                 // 3072*2 f32
  float* rv       = (float*)((char*)d_ws + P_BYTES + 24576);         // 512 f32
  float* D        = (float*)((char*)d_ws + P_BYTES + 24576 + 2048);  // 16 f32

  hipLaunchKernelGGL(k_main, dim3(16 * GG * YT), dim3(THREADS1), 0, stream,
                     x, dw_w, dw_b, gn_w, proj_w, P, partials);
  hipLaunchKernelGGL(k_coef, dim3(1), dim3(512), 0, stream,
                     partials, dw_b, gn_w, gn_b, proj_w, proj_b, rv, D);
  hipLaunchKernelGGL(k_out, dim3(16 * 9), dim3(256), 0, stream,
                     P, rv, D, out);
}

// Round 3
// 58.363 us; speedup vs baseline: 7.1252x; 7.1252x over previous
//
#include <hip/hip_runtime.h>
#include <math.h>

#define HH 96
#define WW 96
#define NPIX (HH*WW)          // 9216
#define CC 320
#define GG 32
#define CPG 10                // channels per group
#define YT 6                  // y-tiles per image
#define TR 16                 // rows per tile
#define TPB 512               // 8 waves: 2 rows/wave, lanes r*32+xcl (xcl<24 active)

// ---------------------------------------------------------------------------
// Kernel 1 (single pass over x): per (b, group, ytile) block.
// Thread (r, xcl) owns 4 pixels of row Y=yt*16+r. Loops the group's 10
// channels; per channel loads 3 float4 rows (clamped+masked, branch-free),
// gets the +-1 halo pixels from wave neighbors via shfl, computes conv u, and
// accumulates:
//   P[b,g,p]  += (proj_w*gn_w)[c] * u          (stats-independent plane)
//   s1,s2     += h, h^2  with h = u + dw_b[c]  (GN statistics)
// ---------------------------------------------------------------------------
__global__ __launch_bounds__(TPB)
void k_main(const float* __restrict__ x, const float* __restrict__ dw_w,
            const float* __restrict__ dw_b, const float* __restrict__ gn_w,
            const float* __restrict__ proj_w,
            float* __restrict__ P, float* __restrict__ partials) {
  const int bid = blockIdx.x;
  const int yt = bid % YT;
  const int t  = bid / YT;
  const int gr = t & 31;
  const int b  = t >> 5;

  __shared__ float wsm[CPG * 9], ssm[CPG], bsm[CPG];
  const int tid = threadIdx.x;
  if (tid < CPG * 9) wsm[tid] = dw_w[gr * CPG * 9 + tid];
  if (tid < CPG) {
    int c = gr * CPG + tid;
    ssm[tid] = proj_w[c] * gn_w[c];
    bsm[tid] = dw_b[c];
  }
  __syncthreads();

  const int lane = tid & 63;
  const int xcl  = tid & 31;            // 0..31; active if <24
  const int r    = tid >> 5;            // row within tile, 0..15
  const bool active = xcl < 24;
  const float mact  = active ? 1.f : 0.f;
  const int xc  = min(xcl, 23);         // clamp inactive lanes to a safe addr
  const int Y   = yt * TR + r;

  const float mtop = (Y > 0)      ? 1.f : 0.f;
  const float mbot = (Y < HH - 1) ? 1.f : 0.f;
  const int ytop = max(Y - 1, 0);
  const int ybot = min(Y + 1, HH - 1);
  const float mlft = (xcl > 0)  ? 1.f : 0.f;   // left halo exists in-image
  const float mrgt = (xcl < 23) ? 1.f : 0.f;   // right halo exists in-image
  const int lm1 = (lane >= 1)  ? lane - 1 : lane;   // safe src lanes
  const int lp1 = (lane <= 62) ? lane + 1 : lane;

  const size_t off_t = (size_t)ytop * WW + xc * 4;
  const size_t off_m = (size_t)Y    * WW + xc * 4;
  const size_t off_b = (size_t)ybot * WW + xc * 4;
  const float* xg = x + ((size_t)(b * CC + gr * CPG)) * NPIX;

  float p0 = 0.f, p1 = 0.f, p2 = 0.f, p3 = 0.f, s1 = 0.f, s2 = 0.f;

  #pragma unroll 1
  for (int cl = 0; cl < CPG; ++cl) {
    const float* img = xg + cl * NPIX;
    float4 vt = *(const float4*)(img + off_t);
    float4 vm = *(const float4*)(img + off_m);
    float4 vb = *(const float4*)(img + off_b);
    vt.x *= mtop; vt.y *= mtop; vt.z *= mtop; vt.w *= mtop;
    vb.x *= mbot; vb.y *= mbot; vb.z *= mbot; vb.w *= mbot;

    // halo pixels from wave neighbors (rows are contained in half-waves)
    float tl = __shfl(vt.w, lm1) * mlft;
    float ml = __shfl(vm.w, lm1) * mlft;
    float bl = __shfl(vb.w, lm1) * mlft;
    float tr_ = __shfl(vt.x, lp1) * mrgt;
    float mr = __shfl(vm.x, lp1) * mrgt;
    float br = __shfl(vb.x, lp1) * mrgt;

    const float* wp = &wsm[cl * 9];
    const float w0 = wp[0], w1 = wp[1], w2 = wp[2];
    const float w3 = wp[3], w4 = wp[4], w5 = wp[5];
    const float w6 = wp[6], w7 = wp[7], w8 = wp[8];

    // conv for the 4 owned pixels
    float u0 = w0*tl   + w1*vt.x + w2*vt.y
             + w3*ml   + w4*vm.x + w5*vm.y
             + w6*bl   + w7*vb.x + w8*vb.y;
    float u1 = w0*vt.x + w1*vt.y + w2*vt.z
             + w3*vm.x + w4*vm.y + w5*vm.z
             + w6*vb.x + w7*vb.y + w8*vb.z;
    float u2 = w0*vt.y + w1*vt.z + w2*vt.w
             + w3*vm.y + w4*vm.z + w5*vm.w
             + w6*vb.y + w7*vb.z + w8*vb.w;
    float u3 = w0*vt.z + w1*vt.w + w2*tr_
             + w3*vm.z + w4*vm.w + w5*mr
             + w6*vb.z + w7*vb.w + w8*br;

    const float sc = ssm[cl], bias = bsm[cl];
    p0 = fmaf(sc, u0, p0);
    p1 = fmaf(sc, u1, p1);
    p2 = fmaf(sc, u2, p2);
    p3 = fmaf(sc, u3, p3);
    float h0 = u0 + bias, h1 = u1 + bias, h2 = u2 + bias, h3 = u3 + bias;
    s1 += mact * ((h0 + h1) + (h2 + h3));
    s2 += mact * (fmaf(h0, h0, h1 * h1) + fmaf(h2, h2, h3 * h3));
  }

  if (active) {
    size_t pidx = ((size_t)(b * GG + gr)) * NPIX + (size_t)Y * WW + xcl * 4;
    *(float4*)&P[pidx] = make_float4(p0, p1, p2, p3);
  }

  // block-reduce s1,s2 (8 waves)
  #pragma unroll
  for (int off = 32; off; off >>= 1) {
    s1 += __shfl_down(s1, off);
    s2 += __shfl_down(s2, off);
  }
  __shared__ float r1[8], r2[8];
  if ((tid & 63) == 0) { r1[tid >> 6] = s1; r2[tid >> 6] = s2; }
  __syncthreads();
  if (tid == 0) {
    float a = 0.f, q = 0.f;
    #pragma unroll
    for (int i = 0; i < 8; ++i) { a += r1[i]; q += r2[i]; }
    size_t o = (((size_t)(b * GG + gr)) * YT + yt) * 2;
    partials[o]     = a;
    partials[o + 1] = q;
  }
}

// ---------------------------------------------------------------------------
// Kernel 2: combine partial stats -> rinv per (b,group); per-batch scalar D.
// One block, 512 threads = (b,group).
// ---------------------------------------------------------------------------
__global__ __launch_bounds__(512)
void k_coef(const float* __restrict__ partials, const float* __restrict__ dw_b,
            const float* __restrict__ gn_w, const float* __restrict__ gn_b,
            const float* __restrict__ proj_w, const float* __restrict__ proj_b,
            float* __restrict__ rv, float* __restrict__ D) {
  const int tid = threadIdx.x;        // 0..511
  const int b = tid >> 5, gr = tid & 31;
  float s1 = 0.f, s2 = 0.f;
  #pragma unroll
  for (int t = 0; t < YT; ++t) {
    size_t o = (((size_t)(b * GG + gr)) * YT + t) * 2;
    s1 += partials[o];
    s2 += partials[o + 1];
  }
  const float invN = 1.f / (float)(CPG * NPIX);
  float mean = s1 * invN;
  float var  = s2 * invN - mean * mean;
  float rinv = rsqrtf(var + 1e-5f);
  float K = 0.f, E = 0.f;
  #pragma unroll
  for (int i = 0; i < CPG; ++i) {
    int c = gr * CPG + i;
    float pg = proj_w[c] * gn_w[c];
    K = fmaf(pg, dw_b[c] - mean, K);
    E = fmaf(proj_w[c], gn_b[c], E);
  }
  rv[tid] = rinv;
  float contrib = fmaf(rinv, K, E);
  #pragma unroll
  for (int m = 16; m; m >>= 1) contrib += __shfl_xor(contrib, m, 32);
  if (gr == 0) D[b] = contrib + proj_b[0];
}

// ---------------------------------------------------------------------------
// Kernel 3: out[b,p] = sigmoid( sum_g rv[b,g]*P[b,g,p] + D[b] )
// 144 blocks x 256 threads, float4 per thread.
// ---------------------------------------------------------------------------
__global__ __launch_bounds__(256)
void k_out(const float* __restrict__ P, const float* __restrict__ rv,
           const float* __restrict__ D, float* __restrict__ out) {
  const int b   = blockIdx.x / 9;
  const int blk = blockIdx.x % 9;
  __shared__ float rs[GG];
  __shared__ float Ds;
  if (threadIdx.x < GG) rs[threadIdx.x] = rv[b * GG + threadIdx.x];
  if (threadIdx.x == 0) Ds = D[b];
  __syncthreads();

  const int p = (blk * 256 + threadIdx.x) * 4;    // 9*256*4 = 9216
  const float* Pb = P + (size_t)b * GG * NPIX + p;
  float g0 = 0.f, g1 = 0.f, g2 = 0.f, g3 = 0.f;
  #pragma unroll 8
  for (int gr = 0; gr < GG; ++gr) {
    float4 v = *(const float4*)(Pb + (size_t)gr * NPIX);
    float rr = rs[gr];
    g0 = fmaf(rr, v.x, g0);
    g1 = fmaf(rr, v.y, g1);
    g2 = fmaf(rr, v.z, g2);
    g3 = fmaf(rr, v.w, g3);
  }
  const float d = Ds;
  float4 o;
  o.x = 1.f / (1.f + expf(-(g0 + d)));
  o.y = 1.f / (1.f + expf(-(g1 + d)));
  o.z = 1.f / (1.f + expf(-(g2 + d)));
  o.w = 1.f / (1.f + expf(-(g3 + d)));
  *(float4*)&out[(size_t)b * NPIX + p] = o;
}

// ---------------------------------------------------------------------------
extern "C" void kernel_launch(void* const* d_in, const int* in_sizes, int n_in,
                              void* d_out, int out_size, void* d_ws, size_t ws_size,
                              hipStream_t stream) {
  const float* x      = (const float*)d_in[0];
  const float* dw_w   = (const float*)d_in[1];
  const float* dw_b   = (const float*)d_in[2];
  const float* gn_w   = (const float*)d_in[3];
  const float* gn_b   = (const float*)d_in[4];
  const float* proj_w = (const float*)d_in[5];
  const float* proj_b = (const float*)d_in[6];
  float* out = (float*)d_out;

  // workspace layout
  const size_t P_BYTES = (size_t)16 * GG * NPIX * 4;     // 18,874,368
  float* P        = (float*)d_ws;
  float* partials = (float*)((char*)d_ws + P_BYTES);                 // 3072*2 f32
  float* rv       = (float*)((char*)d_ws + P_BYTES + 24576);         // 512 f32
  float* D        = (float*)((char*)d_ws + P_BYTES + 24576 + 2048);  // 16 f32

  hipLaunchKernelGGL(k_main, dim3(16 * GG * YT), dim3(TPB), 0, stream,
                     x, dw_w, dw_b, gn_w, proj_w, P, partials);
  hipLaunchKernelGGL(k_coef, dim3(1), dim3(512), 0, stream,
                     partials, dw_b, gn_w, gn_b, proj_w, proj_b, rv, D);
  hipLaunchKernelGGL(k_out, dim3(16 * 9), dim3(256), 0, stream,
                     P, rv, D, out);
}

// Round 4
// 52.254 us; speedup vs baseline: 7.9581x; 1.1169x over previous
//
#include <hip/hip_runtime.h>
#include <math.h>

#define HH 96
#define WW 96
#define NPIX (HH*WW)          // 9216
#define CC 320
#define GG 32
#define CPG 10                // channels per group
#define YT 3                  // y-tiles per image (32 rows each)
#define TPB 512               // 8 waves; thread = (row-pair r=tid>>5, xcl=tid&31)

// ---------------------------------------------------------------------------
// Kernel 1 (single pass over x): per (b, group, ytile=32rows) block.
// Thread (r, xcl) owns rows Y0=yt*32+2r, Y1=Y0+1, pixels [xcl*4, xcl*4+4).
// Per channel: 4 float4 row loads (A=Y0-1, B=Y0, C=Y1, D=Y1+1, clamped+masked),
// halo pixels via wave shfl, 3x3 conv for 8 px, accumulating
//   P[b,g,p]  += (proj_w*gn_w)[c] * u          (stats-independent plane)
//   s1,s2     += h, h^2  with h = u + dw_b[c]  (GN statistics)
// Next channel's 4 loads are software-prefetched (double-buffered registers).
// ---------------------------------------------------------------------------
__global__ __launch_bounds__(TPB)
void k_main(const float* __restrict__ x, const float* __restrict__ dw_w,
            const float* __restrict__ dw_b, const float* __restrict__ gn_w,
            const float* __restrict__ proj_w,
            float* __restrict__ P, float* __restrict__ partials) {
  const int bid = blockIdx.x;
  const int yt = bid % YT;
  const int t  = bid / YT;
  const int gr = t & 31;
  const int b  = t >> 5;

  __shared__ float wsm[CPG * 9], ssm[CPG], bsm[CPG];
  const int tid = threadIdx.x;
  if (tid < CPG * 9) wsm[tid] = dw_w[gr * CPG * 9 + tid];
  if (tid < CPG) {
    int c = gr * CPG + tid;
    ssm[tid] = proj_w[c] * gn_w[c];
    bsm[tid] = dw_b[c];
  }
  __syncthreads();

  const int lane = tid & 63;
  const int xcl  = tid & 31;            // 0..31; active if <24
  const int r    = tid >> 5;            // row-pair index 0..15
  const bool active = xcl < 24;
  const float mact  = active ? 1.f : 0.f;
  const int xc = min(xcl, 23);          // clamp inactive lanes to safe addr
  const int Y0 = yt * 32 + 2 * r;
  const int Y1 = Y0 + 1;

  const float ma = (Y0 > 0)      ? 1.f : 0.f;
  const float md = (Y1 < HH - 1) ? 1.f : 0.f;
  const int ya = max(Y0 - 1, 0);
  const int yd = min(Y1 + 1, HH - 1);
  const float mlft = (xcl > 0)  ? 1.f : 0.f;
  const float mrgt = (xcl < 23) ? 1.f : 0.f;
  const int lm1 = (xcl >= 1) ? lane - 1 : lane;   // stay within the row
  const int lp1 = (xcl < 31) ? lane + 1 : lane;

  const size_t offa = (size_t)ya * WW + xc * 4;
  const size_t offb = (size_t)Y0 * WW + xc * 4;
  const size_t offc = (size_t)Y1 * WW + xc * 4;
  const size_t offd = (size_t)yd * WW + xc * 4;
  const float* xg = x + ((size_t)(b * CC + gr * CPG)) * NPIX;

  float p0=0.f,p1=0.f,p2=0.f,p3=0.f,p4=0.f,p5=0.f,p6=0.f,p7=0.f;
  float s1 = 0.f, s2 = 0.f;

  // prologue: load channel 0
  float4 A = *(const float4*)(xg + offa);
  float4 B = *(const float4*)(xg + offb);
  float4 C = *(const float4*)(xg + offc);
  float4 D = *(const float4*)(xg + offd);

  #pragma unroll 1
  for (int ch = 0; ch < CPG; ++ch) {
    // prefetch next channel (clamped re-load of last channel on final iter)
    const float* nimg = xg + (size_t)min(ch + 1, CPG - 1) * NPIX;
    float4 nA = *(const float4*)(nimg + offa);
    float4 nB = *(const float4*)(nimg + offb);
    float4 nC = *(const float4*)(nimg + offc);
    float4 nD = *(const float4*)(nimg + offd);

    // mask out-of-image rows
    A.x *= ma; A.y *= ma; A.z *= ma; A.w *= ma;
    D.x *= md; D.y *= md; D.z *= md; D.w *= md;

    // halo pixels from wave neighbors
    float al = __shfl(A.w, lm1) * mlft;
    float bl = __shfl(B.w, lm1) * mlft;
    float cl2 = __shfl(C.w, lm1) * mlft;
    float dl = __shfl(D.w, lm1) * mlft;
    float ar = __shfl(A.x, lp1) * mrgt;
    float br = __shfl(B.x, lp1) * mrgt;
    float cr = __shfl(C.x, lp1) * mrgt;
    float dr = __shfl(D.x, lp1) * mrgt;

    const float* wp = &wsm[ch * 9];
    const float w0 = wp[0], w1 = wp[1], w2 = wp[2];
    const float w3 = wp[3], w4 = wp[4], w5 = wp[5];
    const float w6 = wp[6], w7 = wp[7], w8 = wp[8];

    // row Y0 (inputs A,B,C)
    float u0 = w0*al  + w1*A.x + w2*A.y + w3*bl  + w4*B.x + w5*B.y + w6*cl2 + w7*C.x + w8*C.y;
    float u1 = w0*A.x + w1*A.y + w2*A.z + w3*B.x + w4*B.y + w5*B.z + w6*C.x + w7*C.y + w8*C.z;
    float u2 = w0*A.y + w1*A.z + w2*A.w + w3*B.y + w4*B.z + w5*B.w + w6*C.y + w7*C.z + w8*C.w;
    float u3 = w0*A.z + w1*A.w + w2*ar  + w3*B.z + w4*B.w + w5*br  + w6*C.z + w7*C.w + w8*cr;
    // row Y1 (inputs B,C,D)
    float u4 = w0*bl  + w1*B.x + w2*B.y + w3*cl2 + w4*C.x + w5*C.y + w6*dl  + w7*D.x + w8*D.y;
    float u5 = w0*B.x + w1*B.y + w2*B.z + w3*C.x + w4*C.y + w5*C.z + w6*D.x + w7*D.y + w8*D.z;
    float u6 = w0*B.y + w1*B.z + w2*B.w + w3*C.y + w4*C.z + w5*C.w + w6*D.y + w7*D.z + w8*D.w;
    float u7 = w0*B.z + w1*B.w + w2*br  + w3*C.z + w4*C.w + w5*cr  + w6*D.z + w7*D.w + w8*dr;

    const float sc = ssm[ch], bias = bsm[ch];
    p0 = fmaf(sc, u0, p0); p1 = fmaf(sc, u1, p1);
    p2 = fmaf(sc, u2, p2); p3 = fmaf(sc, u3, p3);
    p4 = fmaf(sc, u4, p4); p5 = fmaf(sc, u5, p5);
    p6 = fmaf(sc, u6, p6); p7 = fmaf(sc, u7, p7);

    float h0 = u0 + bias, h1 = u1 + bias, h2 = u2 + bias, h3 = u3 + bias;
    float h4 = u4 + bias, h5 = u5 + bias, h6 = u6 + bias, h7 = u7 + bias;
    s1 += mact * (((h0 + h1) + (h2 + h3)) + ((h4 + h5) + (h6 + h7)));
    float q0 = fmaf(h0, h0, h1 * h1), q1 = fmaf(h2, h2, h3 * h3);
    float q2 = fmaf(h4, h4, h5 * h5), q3 = fmaf(h6, h6, h7 * h7);
    s2 += mact * ((q0 + q1) + (q2 + q3));

    A = nA; B = nB; C = nC; D = nD;
  }

  if (active) {
    size_t base = ((size_t)(b * GG + gr)) * NPIX + (size_t)Y0 * WW + xcl * 4;
    *(float4*)&P[base]      = make_float4(p0, p1, p2, p3);
    *(float4*)&P[base + WW] = make_float4(p4, p5, p6, p7);
  }

  // block-reduce s1,s2 (8 waves)
  #pragma unroll
  for (int off = 32; off; off >>= 1) {
    s1 += __shfl_down(s1, off);
    s2 += __shfl_down(s2, off);
  }
  __shared__ float r1[8], r2[8];
  if ((tid & 63) == 0) { r1[tid >> 6] = s1; r2[tid >> 6] = s2; }
  __syncthreads();
  if (tid == 0) {
    float a = 0.f, q = 0.f;
    #pragma unroll
    for (int i = 0; i < 8; ++i) { a += r1[i]; q += r2[i]; }
    size_t o = (((size_t)(b * GG + gr)) * YT + yt) * 2;
    partials[o]     = a;
    partials[o + 1] = q;
  }
}

// ---------------------------------------------------------------------------
// Kernel 2: fused coef + output. Each block (9 per batch) recomputes its
// batch's 32 rinv values + scalar D from the tiny partials array, then
// out[b,p] = sigmoid( sum_g rinv[g]*P[b,g,p] + D ).
// ---------------------------------------------------------------------------
__global__ __launch_bounds__(256)
void k_out(const float* __restrict__ P, const float* __restrict__ partials,
           const float* __restrict__ dw_b, const float* __restrict__ gn_w,
           const float* __restrict__ gn_b, const float* __restrict__ proj_w,
           const float* __restrict__ proj_b, float* __restrict__ out) {
  const int b   = blockIdx.x / 9;
  const int blk = blockIdx.x % 9;
  __shared__ float rs[GG];
  __shared__ float Ds;

  if (threadIdx.x < GG) {
    const int gr = threadIdx.x;
    float s1 = 0.f, s2 = 0.f;
    #pragma unroll
    for (int t = 0; t < YT; ++t) {
      size_t o = (((size_t)(b * GG + gr)) * YT + t) * 2;
      s1 += partials[o];
      s2 += partials[o + 1];
    }
    const float invN = 1.f / (float)(CPG * NPIX);
    float mean = s1 * invN;
    float var  = s2 * invN - mean * mean;
    float rinv = rsqrtf(var + 1e-5f);
    rs[gr] = rinv;
    float K = 0.f, E = 0.f;
    #pragma unroll
    for (int i = 0; i < CPG; ++i) {
      int c = gr * CPG + i;
      float pg = proj_w[c] * gn_w[c];
      K = fmaf(pg, dw_b[c] - mean, K);
      E = fmaf(proj_w[c], gn_b[c], E);
    }
    float contrib = fmaf(rinv, K, E);
    #pragma unroll
    for (int m = 16; m; m >>= 1) contrib += __shfl_xor(contrib, m, 32);
    if (gr == 0) Ds = contrib + proj_b[0];
  }
  __syncthreads();

  const int p = (blk * 256 + threadIdx.x) * 4;    // 9*256*4 = 9216
  const float* Pb = P + (size_t)b * GG * NPIX + p;
  float g0 = 0.f, g1 = 0.f, g2 = 0.f, g3 = 0.f;
  #pragma unroll 8
  for (int gr = 0; gr < GG; ++gr) {
    float4 v = *(const float4*)(Pb + (size_t)gr * NPIX);
    float rr = rs[gr];
    g0 = fmaf(rr, v.x, g0);
    g1 = fmaf(rr, v.y, g1);
    g2 = fmaf(rr, v.z, g2);
    g3 = fmaf(rr, v.w, g3);
  }
  const float d = Ds;
  float4 o;
  o.x = 1.f / (1.f + expf(-(g0 + d)));
  o.y = 1.f / (1.f + expf(-(g1 + d)));
  o.z = 1.f / (1.f + expf(-(g2 + d)));
  o.w = 1.f / (1.f + expf(-(g3 + d)));
  *(float4*)&out[(size_t)b * NPIX + p] = o;
}

// ---------------------------------------------------------------------------
extern "C" void kernel_launch(void* const* d_in, const int* in_sizes, int n_in,
                              void* d_out, int out_size, void* d_ws, size_t ws_size,
                              hipStream_t stream) {
  const float* x      = (const float*)d_in[0];
  const float* dw_w   = (const float*)d_in[1];
  const float* dw_b   = (const float*)d_in[2];
  const float* gn_w   = (const float*)d_in[3];
  const float* gn_b   = (const float*)d_in[4];
  const float* proj_w = (const float*)d_in[5];
  const float* proj_b = (const float*)d_in[6];
  float* out = (float*)d_out;

  const size_t P_BYTES = (size_t)16 * GG * NPIX * 4;     // 18,874,368
  float* P        = (float*)d_ws;
  float* partials = (float*)((char*)d_ws + P_BYTES);     // 512*YT*2 f32

  hipLaunchKernelGGL(k_main, dim3(16 * GG * YT), dim3(TPB), 0, stream,
                     x, dw_w, dw_b, gn_w, proj_w, P, partials);
  hipLaunchKernelGGL(k_out, dim3(16 * 9), dim3(256), 0, stream,
                     P, partials, dw_b, gn_w, gn_b, proj_w, proj_b, out);
}

// Round 5
// 51.760 us; speedup vs baseline: 8.0342x; 1.0096x over previous
//
#include <hip/hip_runtime.h>
#include <math.h>

#define HH 96
#define WW 96
#define NPIX (HH*WW)          // 9216
#define CC 320
#define GG 32
#define CPG 10                // channels per group
#define TPB 512               // 8 waves; thread = (row-pair r=tid>>5, xcl=tid&31)

typedef _Float16 half4v __attribute__((ext_vector_type(4)));

// ---------------------------------------------------------------------------
// Kernel 1 (single pass over x): one block per (b, group), all 96 rows.
// Thread (r, xcl) owns row-pairs Y0 in {2r, 2r+32, 2r+64}, px [xcl*4, xcl*4+4).
// Per channel, per pair: 4 float4 row loads (clamped+masked), halo via shfl,
// 3x3 conv for 8 px, accumulating
//   p[grp][j]  += (proj_w*gn_w)[c] * u          (stats-independent plane)
//   s1,s2      += h, h^2  with h = u + dw_b[c]  (GN statistics)
// P stored once at the end as fp16 (error budget: logit slope 0.018,
// fp16 P adds ~1e-5 logit error vs 0.02 allowed).
// ---------------------------------------------------------------------------
__global__ __launch_bounds__(TPB)
void k_main(const float* __restrict__ x, const float* __restrict__ dw_w,
            const float* __restrict__ dw_b, const float* __restrict__ gn_w,
            const float* __restrict__ proj_w,
            _Float16* __restrict__ P, float* __restrict__ partials) {
  const int gr = blockIdx.x & 31;
  const int b  = blockIdx.x >> 5;

  __shared__ float wsm[CPG * 9], ssm[CPG], bsm[CPG];
  const int tid = threadIdx.x;
  if (tid < CPG * 9) wsm[tid] = dw_w[gr * CPG * 9 + tid];
  if (tid < CPG) {
    int c = gr * CPG + tid;
    ssm[tid] = proj_w[c] * gn_w[c];
    bsm[tid] = dw_b[c];
  }
  __syncthreads();

  const int lane = tid & 63;
  const int xcl  = tid & 31;            // 0..31; active if <24
  const int r    = tid >> 5;            // row-pair base 0..15
  const bool active = xcl < 24;
  const float mact  = active ? 1.f : 0.f;
  const int xc = min(xcl, 23);          // clamp inactive lanes to safe addr
  const float mlft = (xcl > 0)  ? 1.f : 0.f;
  const float mrgt = (xcl < 23) ? 1.f : 0.f;
  const int lm1 = (xcl >= 1) ? lane - 1 : lane;
  const int lp1 = (xcl < 31) ? lane + 1 : lane;

  // per-group row geometry (compile-time unrolled, 3 groups)
  int   offa[3], offb[3], offc[3], offd[3];
  float ma[3], md[3];
  #pragma unroll
  for (int g3 = 0; g3 < 3; ++g3) {
    const int Y0 = 2 * r + 32 * g3;
    const int Y1 = Y0 + 1;
    ma[g3] = (Y0 > 0)      ? 1.f : 0.f;
    md[g3] = (Y1 < HH - 1) ? 1.f : 0.f;
    const int ya = max(Y0 - 1, 0);
    const int yd = min(Y1 + 1, HH - 1);
    offa[g3] = ya * WW + xc * 4;
    offb[g3] = Y0 * WW + xc * 4;
    offc[g3] = Y1 * WW + xc * 4;
    offd[g3] = yd * WW + xc * 4;
  }
  const float* xg = x + ((size_t)(b * CC + gr * CPG)) * NPIX;

  float p[24];
  #pragma unroll
  for (int i = 0; i < 24; ++i) p[i] = 0.f;
  float s1 = 0.f, s2 = 0.f;

  #pragma unroll 1
  for (int ch = 0; ch < CPG; ++ch) {
    const float* img = xg + ch * NPIX;
    const float* wp = &wsm[ch * 9];
    const float w0 = wp[0], w1 = wp[1], w2 = wp[2];
    const float w3 = wp[3], w4 = wp[4], w5 = wp[5];
    const float w6 = wp[6], w7 = wp[7], w8 = wp[8];
    const float sc = ssm[ch], bias = bsm[ch];

    #pragma unroll
    for (int g3 = 0; g3 < 3; ++g3) {
      float4 A = *(const float4*)(img + offa[g3]);
      float4 B = *(const float4*)(img + offb[g3]);
      float4 C = *(const float4*)(img + offc[g3]);
      float4 D = *(const float4*)(img + offd[g3]);
      const float mma = ma[g3], mmd = md[g3];
      A.x *= mma; A.y *= mma; A.z *= mma; A.w *= mma;
      D.x *= mmd; D.y *= mmd; D.z *= mmd; D.w *= mmd;

      float al = __shfl(A.w, lm1) * mlft;
      float bl = __shfl(B.w, lm1) * mlft;
      float cl2 = __shfl(C.w, lm1) * mlft;
      float dl = __shfl(D.w, lm1) * mlft;
      float ar = __shfl(A.x, lp1) * mrgt;
      float br = __shfl(B.x, lp1) * mrgt;
      float cr = __shfl(C.x, lp1) * mrgt;
      float dr = __shfl(D.x, lp1) * mrgt;

      // row Y0 (A,B,C)
      float u0 = w0*al  + w1*A.x + w2*A.y + w3*bl  + w4*B.x + w5*B.y + w6*cl2 + w7*C.x + w8*C.y;
      float u1 = w0*A.x + w1*A.y + w2*A.z + w3*B.x + w4*B.y + w5*B.z + w6*C.x + w7*C.y + w8*C.z;
      float u2 = w0*A.y + w1*A.z + w2*A.w + w3*B.y + w4*B.z + w5*B.w + w6*C.y + w7*C.z + w8*C.w;
      float u3 = w0*A.z + w1*A.w + w2*ar  + w3*B.z + w4*B.w + w5*br  + w6*C.z + w7*C.w + w8*cr;
      // row Y1 (B,C,D)
      float u4 = w0*bl  + w1*B.x + w2*B.y + w3*cl2 + w4*C.x + w5*C.y + w6*dl  + w7*D.x + w8*D.y;
      float u5 = w0*B.x + w1*B.y + w2*B.z + w3*C.x + w4*C.y + w5*C.z + w6*D.x + w7*D.y + w8*D.z;
      float u6 = w0*B.y + w1*B.z + w2*B.w + w3*C.y + w4*C.z + w5*C.w + w6*D.y + w7*D.z + w8*D.w;
      float u7 = w0*B.z + w1*B.w + w2*br  + w3*C.z + w4*C.w + w5*cr  + w6*D.z + w7*D.w + w8*dr;

      p[g3*8+0] = fmaf(sc, u0, p[g3*8+0]);
      p[g3*8+1] = fmaf(sc, u1, p[g3*8+1]);
      p[g3*8+2] = fmaf(sc, u2, p[g3*8+2]);
      p[g3*8+3] = fmaf(sc, u3, p[g3*8+3]);
      p[g3*8+4] = fmaf(sc, u4, p[g3*8+4]);
      p[g3*8+5] = fmaf(sc, u5, p[g3*8+5]);
      p[g3*8+6] = fmaf(sc, u6, p[g3*8+6]);
      p[g3*8+7] = fmaf(sc, u7, p[g3*8+7]);

      float h0 = u0 + bias, h1 = u1 + bias, h2 = u2 + bias, h3 = u3 + bias;
      float h4 = u4 + bias, h5 = u5 + bias, h6 = u6 + bias, h7 = u7 + bias;
      s1 += mact * (((h0 + h1) + (h2 + h3)) + ((h4 + h5) + (h6 + h7)));
      float q0 = fmaf(h0, h0, h1 * h1), q1 = fmaf(h2, h2, h3 * h3);
      float q2 = fmaf(h4, h4, h5 * h5), q3 = fmaf(h6, h6, h7 * h7);
      s2 += mact * ((q0 + q1) + (q2 + q3));
    }
  }

  if (active) {
    _Float16* Pp = P + ((size_t)(b * GG + gr)) * NPIX;
    #pragma unroll
    for (int g3 = 0; g3 < 3; ++g3) {
      const int Y0 = 2 * r + 32 * g3;
      half4v h0, h1;
      h0.x = (_Float16)p[g3*8+0]; h0.y = (_Float16)p[g3*8+1];
      h0.z = (_Float16)p[g3*8+2]; h0.w = (_Float16)p[g3*8+3];
      h1.x = (_Float16)p[g3*8+4]; h1.y = (_Float16)p[g3*8+5];
      h1.z = (_Float16)p[g3*8+6]; h1.w = (_Float16)p[g3*8+7];
      *(half4v*)&Pp[(size_t)Y0 * WW + xcl * 4]       = h0;
      *(half4v*)&Pp[(size_t)(Y0 + 1) * WW + xcl * 4] = h1;
    }
  }

  // block-reduce s1,s2 (8 waves)
  #pragma unroll
  for (int off = 32; off; off >>= 1) {
    s1 += __shfl_down(s1, off);
    s2 += __shfl_down(s2, off);
  }
  __shared__ float r1[8], r2[8];
  if ((tid & 63) == 0) { r1[tid >> 6] = s1; r2[tid >> 6] = s2; }
  __syncthreads();
  if (tid == 0) {
    float a = 0.f, q = 0.f;
    #pragma unroll
    for (int i = 0; i < 8; ++i) { a += r1[i]; q += r2[i]; }
    partials[blockIdx.x * 2]     = a;
    partials[blockIdx.x * 2 + 1] = q;
  }
}

// ---------------------------------------------------------------------------
// Kernel 2: fused coef + output. Each block (18 per batch) recomputes its
// batch's 32 rinv values + scalar D from partials, then
// out[b,p] = sigmoid( sum_g rinv[g]*P[b,g,p] + D ).  128 thr, 4 px/thread.
// ---------------------------------------------------------------------------
__global__ __launch_bounds__(128)
void k_out(const _Float16* __restrict__ P, const float* __restrict__ partials,
           const float* __restrict__ dw_b, const float* __restrict__ gn_w,
           const float* __restrict__ gn_b, const float* __restrict__ proj_w,
           const float* __restrict__ proj_b, float* __restrict__ out) {
  const int b   = blockIdx.x / 18;
  const int blk = blockIdx.x % 18;
  __shared__ float rs[GG];
  __shared__ float Ds;

  if (threadIdx.x < GG) {
    const int gr = threadIdx.x;
    float s1 = partials[(b * GG + gr) * 2];
    float s2 = partials[(b * GG + gr) * 2 + 1];
    const float invN = 1.f / (float)(CPG * NPIX);
    float mean = s1 * invN;
    float var  = s2 * invN - mean * mean;
    float rinv = rsqrtf(var + 1e-5f);
    rs[gr] = rinv;
    float K = 0.f, E = 0.f;
    #pragma unroll
    for (int i = 0; i < CPG; ++i) {
      int c = gr * CPG + i;
      float pg = proj_w[c] * gn_w[c];
      K = fmaf(pg, dw_b[c] - mean, K);
      E = fmaf(proj_w[c], gn_b[c], E);
    }
    float contrib = fmaf(rinv, K, E);
    #pragma unroll
    for (int m = 16; m; m >>= 1) contrib += __shfl_xor(contrib, m, 32);
    if (gr == 0) Ds = contrib + proj_b[0];
  }
  __syncthreads();

  const int p = (blk * 128 + threadIdx.x) * 4;    // 18*128*4 = 9216
  const _Float16* Pb = P + (size_t)b * GG * NPIX + p;
  float g0 = 0.f, g1 = 0.f, g2 = 0.f, g3 = 0.f;
  #pragma unroll
  for (int gr = 0; gr < GG; ++gr) {
    half4v v = *(const half4v*)(Pb + (size_t)gr * NPIX);
    float rr = rs[gr];
    g0 = fmaf(rr, (float)v.x, g0);
    g1 = fmaf(rr, (float)v.y, g1);
    g2 = fmaf(rr, (float)v.z, g2);
    g3 = fmaf(rr, (float)v.w, g3);
  }
  const float d = Ds;
  float4 o;
  o.x = 1.f / (1.f + expf(-(g0 + d)));
  o.y = 1.f / (1.f + expf(-(g1 + d)));
  o.z = 1.f / (1.f + expf(-(g2 + d)));
  o.w = 1.f / (1.f + expf(-(g3 + d)));
  *(float4*)&out[(size_t)b * NPIX + p] = o;
}

// ---------------------------------------------------------------------------
extern "C" void kernel_launch(void* const* d_in, const int* in_sizes, int n_in,
                              void* d_out, int out_size, void* d_ws, size_t ws_size,
                              hipStream_t stream) {
  const float* x      = (const float*)d_in[0];
  const float* dw_w   = (const float*)d_in[1];
  const float* dw_b   = (const float*)d_in[2];
  const float* gn_w   = (const float*)d_in[3];
  const float* gn_b   = (const float*)d_in[4];
  const float* proj_w = (const float*)d_in[5];
  const float* proj_b = (const float*)d_in[6];
  float* out = (float*)d_out;

  const size_t P_BYTES = (size_t)16 * GG * NPIX * 2;     // fp16: 9,437,184 B
  _Float16* P     = (_Float16*)d_ws;
  float* partials = (float*)((char*)d_ws + P_BYTES);     // 512*2 f32

  hipLaunchKernelGGL(k_main, dim3(16 * GG), dim3(TPB), 0, stream,
                     x, dw_w, dw_b, gn_w, proj_w, P, partials);
  hipLaunchKernelGGL(k_out, dim3(16 * 18), dim3(128), 0, stream,
                     P, partials, dw_b, gn_w, gn_b, proj_w, proj_b, out);
}